// Round 1
// baseline (24621.216 us; speedup 1.0000x reference)
//
#include <hip/hip_runtime.h>
#include <math.h>

#define B_    64
#define APER_ 16
#define A_    1024
#define TPAST_ 20
#define TFUT_  30
#define C_    256
#define M_    128
#define N_    256
#define H_    5
#define EMB_  16
#define D_    384
#define TTOT_ 50

__device__ __forceinline__ float sigmoidf_(float x) { return 1.0f / (1.0f + expf(-x)); }
__device__ __forceinline__ float softplusf_(float x) { return (x > 20.0f) ? x : log1pf(expf(x)); }

// ---------------------------------------------------------------------------
// Fused GRU kernel:  Hnew = GRU([X1,X2], Hprev)
//   gi = [X1,X2] @ Wih^T + bih   (Wih: (3G, K1+K2) row-major)
//   gh = Hprev  @ Whh^T + bhh    (Whh: (3G, G))
//   r = sig(gi0+gh0); z = sig(gi1+gh1); n = tanh(gi2 + r*gh2); h' = (1-z)n + z h
// X1 may be null (treated as zeros). X1 rows indexed modulo rowmod1 (broadcast).
// 64x64 output tile per block, 256 threads, 4x4 micro-tile, BK=16.
// Requires: R%64==0, G%64==0, K1%16==0, K2%16==0.
// ---------------------------------------------------------------------------
__device__ __forceinline__ void gru_tile_phase(
    const float* __restrict__ Xp, int K, int rmod, int rowBase,
    const float* __restrict__ Wp, int wld, int wcolOff, int G, int colBase,
    float acc[3][4][4], float* Xs, float* Ws, int tid, int tx, int ty)
{
    const int nkt = K >> 4;
    for (int kt = 0; kt < nkt; ++kt) {
        const int k0 = kt << 4;
        // load X tile: 64 rows x 16 k  (1 float4 per thread)
        {
            int lr = tid >> 2, lk = (tid & 3) << 2;
            int gr = (rowBase + lr) % rmod;
            const float4 v = *(const float4*)(Xp + (size_t)gr * K + k0 + lk);
            float* d = Xs + lr * 17 + lk;
            d[0] = v.x; d[1] = v.y; d[2] = v.z; d[3] = v.w;
        }
        // load W tile: 3 gates x 64 cols x 16 k (3 float4 per thread)
        #pragma unroll
        for (int q = 0; q < 3; ++q) {
            int e4 = (tid + (q << 8)) << 2;
            int g = e4 >> 10;
            int rem = e4 & 1023;
            int wc = rem >> 4, k = rem & 15;
            const float4 v = *(const float4*)(Wp + (size_t)(g * G + colBase + wc) * wld + wcolOff + k0 + k);
            float* d = Ws + g * 1088 + wc * 17 + k;
            d[0] = v.x; d[1] = v.y; d[2] = v.z; d[3] = v.w;
        }
        __syncthreads();
        #pragma unroll
        for (int k = 0; k < 16; ++k) {
            float xv[4];
            #pragma unroll
            for (int i = 0; i < 4; ++i) xv[i] = Xs[(ty * 4 + i) * 17 + k];
            #pragma unroll
            for (int g = 0; g < 3; ++g) {
                #pragma unroll
                for (int j = 0; j < 4; ++j) {
                    float wv = Ws[g * 1088 + (tx * 4 + j) * 17 + k];
                    #pragma unroll
                    for (int i = 0; i < 4; ++i) acc[g][i][j] += xv[i] * wv;
                }
            }
        }
        __syncthreads();
    }
}

__global__ __launch_bounds__(256) void gru_fused(
    const float* __restrict__ X1, int K1, int rowmod1,
    const float* __restrict__ X2, int K2,
    const float* __restrict__ Wih, const float* __restrict__ bih,
    const float* __restrict__ Whh, const float* __restrict__ bhh,
    const float* __restrict__ Hprev, float* __restrict__ Hnew,
    int R, int G)
{
    __shared__ float Xs[64 * 17];
    __shared__ float Ws[3 * 64 * 17];
    const int tid = threadIdx.x;
    const int tx = tid & 15, ty = tid >> 4;
    const int rowBase = blockIdx.x * 64;
    const int colBase = blockIdx.y * 64;
    const int Ktot = K1 + K2;

    float accx[3][4][4];
    float acch[3][4][4];
    #pragma unroll
    for (int g = 0; g < 3; ++g)
        #pragma unroll
        for (int i = 0; i < 4; ++i)
            #pragma unroll
            for (int j = 0; j < 4; ++j) { accx[g][i][j] = 0.f; acch[g][i][j] = 0.f; }

    if (X1 != nullptr && K1 > 0)
        gru_tile_phase(X1, K1, rowmod1, rowBase, Wih, Ktot, 0, G, colBase, accx, Xs, Ws, tid, tx, ty);
    if (X2 != nullptr && K2 > 0)
        gru_tile_phase(X2, K2, R, rowBase, Wih, Ktot, K1, G, colBase, accx, Xs, Ws, tid, tx, ty);
    gru_tile_phase(Hprev, G, R, rowBase, Whh, G, 0, G, colBase, acch, Xs, Ws, tid, tx, ty);

    #pragma unroll
    for (int i = 0; i < 4; ++i) {
        const int row = rowBase + ty * 4 + i;
        #pragma unroll
        for (int j = 0; j < 4; ++j) {
            const int col = colBase + tx * 4 + j;
            float gr = sigmoidf_(accx[0][i][j] + bih[col] + acch[0][i][j] + bhh[col]);
            float gz = sigmoidf_(accx[1][i][j] + bih[G + col] + acch[1][i][j] + bhh[G + col]);
            float gn = tanhf(accx[2][i][j] + bih[2 * G + col] + gr * (acch[2][i][j] + bhh[2 * G + col]));
            float hp = Hprev[(size_t)row * G + col];
            Hnew[(size_t)row * G + col] = (1.f - gz) * gn + gz * hp;
        }
    }
}

// ---------------------------------------------------------------------------
// Generic GEMM: Out(R,Cols) = X(R,K) @ W(Cols,K)^T + bias(Cols)
// R%64==0, K%16==0; Cols guarded.
// ---------------------------------------------------------------------------
__global__ __launch_bounds__(256) void gemm_xt(
    const float* __restrict__ X, const float* __restrict__ W,
    const float* __restrict__ bias, float* __restrict__ Out,
    int R, int Cols, int K)
{
    __shared__ float Xs[64 * 17];
    __shared__ float Ws[64 * 17];
    const int tid = threadIdx.x;
    const int tx = tid & 15, ty = tid >> 4;
    const int rowBase = blockIdx.x * 64;
    const int colBase = blockIdx.y * 64;
    float acc[4][4];
    #pragma unroll
    for (int i = 0; i < 4; ++i)
        #pragma unroll
        for (int j = 0; j < 4; ++j) acc[i][j] = 0.f;

    for (int k0 = 0; k0 < K; k0 += 16) {
        {
            int lr = tid >> 2, lk = (tid & 3) << 2;
            const float4 v = *(const float4*)(X + (size_t)(rowBase + lr) * K + k0 + lk);
            float* d = Xs + lr * 17 + lk;
            d[0] = v.x; d[1] = v.y; d[2] = v.z; d[3] = v.w;
        }
        {
            int wc = tid >> 2, lk = (tid & 3) << 2;
            int col = colBase + wc;
            float4 v = make_float4(0.f, 0.f, 0.f, 0.f);
            if (col < Cols) v = *(const float4*)(W + (size_t)col * K + k0 + lk);
            float* d = Ws + wc * 17 + lk;
            d[0] = v.x; d[1] = v.y; d[2] = v.z; d[3] = v.w;
        }
        __syncthreads();
        #pragma unroll
        for (int k = 0; k < 16; ++k) {
            float xv[4], wv[4];
            #pragma unroll
            for (int i = 0; i < 4; ++i) xv[i] = Xs[(ty * 4 + i) * 17 + k];
            #pragma unroll
            for (int j = 0; j < 4; ++j) wv[j] = Ws[(tx * 4 + j) * 17 + k];
            #pragma unroll
            for (int i = 0; i < 4; ++i)
                #pragma unroll
                for (int j = 0; j < 4; ++j) acc[i][j] += xv[i] * wv[j];
        }
        __syncthreads();
    }
    #pragma unroll
    for (int i = 0; i < 4; ++i) {
        const int row = rowBase + ty * 4 + i;
        #pragma unroll
        for (int j = 0; j < 4; ++j) {
            const int col = colBase + tx * 4 + j;
            if (col < Cols) Out[(size_t)row * Cols + col] = acc[i][j] + bias[col];
        }
    }
}

// ---------------------------------------------------------------------------
// NTM write: per-agent banded content addressing + erase/add. Block per agent.
// wp row layout: [kw(128), beta(1), er(128), ad(128)]
// ---------------------------------------------------------------------------
__global__ __launch_bounds__(256) void write_mem_k(const float* __restrict__ wp,
                                                   float* __restrict__ mem)
{
    const int a = blockIdx.x;
    const int b = a >> 4, p = a & 15;
    __shared__ float kw[128], er[128], ad[128], red[256], ww[16], logit[16];
    __shared__ float beta_s, knorm_s;
    const int tid = threadIdx.x;
    const float* w = wp + (size_t)a * 385;
    if (tid < 128) {
        kw[tid] = tanhf(w[tid]);
        er[tid] = sigmoidf_(w[129 + tid]);
        ad[tid] = tanhf(w[257 + tid]);
    }
    if (tid == 0) beta_s = softplusf_(w[128]);
    __syncthreads();

    red[tid] = (tid < 128) ? kw[tid] * kw[tid] : 0.f;
    __syncthreads();
    for (int s = 128; s > 0; s >>= 1) { if (tid < s) red[tid] += red[tid + s]; __syncthreads(); }
    if (tid == 0) knorm_s = sqrtf(red[0]) + 1e-16f;
    __syncthreads();

    // sims over the agent's 16-slot band: 16 groups of 16 lanes
    const int s = tid >> 4, j = tid & 15;
    float dot = 0.f, ss = 0.f;
    {
        const float* mrow = mem + ((size_t)(b * N_) + p * 16 + s) * M_;
        for (int k = j; k < 128; k += 16) { float v = mrow[k]; dot += kw[k] * v; ss += v * v; }
    }
    red[tid] = dot; __syncthreads();
    for (int st = 8; st > 0; st >>= 1) { if (j < st) red[tid] += red[tid + st]; __syncthreads(); }
    float dotf = red[s * 16];
    __syncthreads();
    red[tid] = ss; __syncthreads();
    for (int st = 8; st > 0; st >>= 1) { if (j < st) red[tid] += red[tid + st]; __syncthreads(); }
    float ssf = red[s * 16];
    if (j == 0) {
        float mn = sqrtf(ssf) + 1e-16f;
        logit[s] = beta_s * (dotf / (mn * knorm_s));
    }
    __syncthreads();
    if (tid == 0) {
        float mx = -1e30f;
        for (int i = 0; i < 16; ++i) mx = fmaxf(mx, logit[i]);
        float sum = 0.f;
        for (int i = 0; i < 16; ++i) { float e = __expf(logit[i] - mx); ww[i] = e; sum += e; }
        float inv = 1.f / sum;
        for (int i = 0; i < 16; ++i) ww[i] *= inv;
    }
    __syncthreads();
    // erase/add within the band (disjoint across agents)
    for (int idx = tid; idx < 16 * 128; idx += 256) {
        int si = idx >> 7, m = idx & 127;
        float* mp = mem + ((size_t)(b * N_) + p * 16 + si) * M_ + m;
        float wwv = ww[si];
        *mp = (*mp) * (1.f - wwv * er[m]) + wwv * ad[m];
    }
}

// ---------------------------------------------------------------------------
// NTM read: per-agent block, loops over H heads. Masked cosine softmax over
// N=256 slots (own band excluded), then weighted sum of memory rows.
// rp row layout per head: [kr(128), beta(1)]
// ---------------------------------------------------------------------------
__global__ __launch_bounds__(256) void read_k(const float* __restrict__ rp,
                                              const float* __restrict__ mem,
                                              float* __restrict__ reads,
                                              float* __restrict__ rbuf)
{
    const int a = blockIdx.x;
    const int b = a >> 4, p = a & 15;
    __shared__ float kr[128], wr[256], red[256];
    __shared__ float beta_s, knorm_s;
    const int tid = threadIdx.x;

    for (int h = 0; h < H_; ++h) {
        const float* rrow = rp + (size_t)a * 645 + h * 129;
        if (tid < 128) kr[tid] = tanhf(rrow[tid]);
        if (tid == 0) beta_s = softplusf_(rrow[128]);
        __syncthreads();
        red[tid] = (tid < 128) ? kr[tid] * kr[tid] : 0.f;
        __syncthreads();
        for (int s = 128; s > 0; s >>= 1) { if (tid < s) red[tid] += red[tid + s]; __syncthreads(); }
        if (tid == 0) knorm_s = sqrtf(red[0]) + 1e-16f;
        __syncthreads();

        // similarity for slot n = tid
        const float* mrow = mem + ((size_t)(b * N_) + tid) * M_;
        float dot = 0.f, ss = 0.f;
        for (int k = 0; k < 128; k += 4) {
            float4 v = *(const float4*)(mrow + k);
            dot += kr[k] * v.x + kr[k + 1] * v.y + kr[k + 2] * v.z + kr[k + 3] * v.w;
            ss += v.x * v.x + v.y * v.y + v.z * v.z + v.w * v.w;
        }
        float lg;
        if ((tid >> 4) == p) lg = -1e30f;
        else {
            float mn = sqrtf(ss) + 1e-16f;
            lg = beta_s * (dot / (mn * knorm_s));
        }
        red[tid] = lg; __syncthreads();
        for (int s = 128; s > 0; s >>= 1) { if (tid < s) red[tid] = fmaxf(red[tid], red[tid + s]); __syncthreads(); }
        float mx = red[0];
        __syncthreads();
        float e = __expf(lg - mx);
        wr[tid] = e; red[tid] = e; __syncthreads();
        for (int s = 128; s > 0; s >>= 1) { if (tid < s) red[tid] += red[tid + s]; __syncthreads(); }
        float inv = 1.f / red[0];

        if (tid < 128) {
            float acc = 0.f;
            const float* mb = mem + (size_t)(b * N_) * M_ + tid;
            for (int n = 0; n < N_; ++n) acc += wr[n] * mb[(size_t)n * M_];
            acc *= inv;
            reads[((size_t)h * A_ + a) * M_ + tid] = acc;
            if (h == 0) rbuf[(size_t)a * M_ + tid] = acc;
        }
        __syncthreads();
    }
}

// ---------------------------------------------------------------------------
// Output projection: (5120,384) @ (2,384)^T + b -> pred_rel[a,h,t,:]
// One wave per row.
// ---------------------------------------------------------------------------
__global__ __launch_bounds__(256) void out_k(const float* __restrict__ hf,
                                             const float* __restrict__ out_w,
                                             const float* __restrict__ out_b,
                                             float* __restrict__ predrel, int t)
{
    const int row = blockIdx.x * 4 + (threadIdx.x >> 6);
    const int lane = threadIdx.x & 63;
    const float* hrow = hf + (size_t)row * D_;
    float a0 = 0.f, a1 = 0.f;
    for (int k = lane; k < D_; k += 64) {
        float v = hrow[k];
        a0 += v * out_w[k];
        a1 += v * out_w[D_ + k];
    }
    for (int off = 32; off > 0; off >>= 1) { a0 += __shfl_down(a0, off); a1 += __shfl_down(a1, off); }
    if (lane == 0) {
        int hh = row >> 10;        // row = hh*1024 + a
        int a = row & 1023;
        float* o = predrel + (((size_t)a * H_ + hh) * TFUT_ + t) * 2;
        o[0] = a0 + out_b[0];
        o[1] = a1 + out_b[1];
    }
}

// pred[a,h,t,:] = past[a,-1,:] + cumsum_t(pred_rel)
__global__ __launch_bounds__(256) void cumsum_k(const float* __restrict__ past,
                                                const float* __restrict__ predrel,
                                                float* __restrict__ pred)
{
    const int idx = blockIdx.x * 256 + threadIdx.x;   // (a*H + h)*2 + c
    if (idx >= A_ * H_ * 2) return;
    const int c = idx & 1;
    const int ah = idx >> 1;
    const int a = ah / H_;
    float acc = past[((size_t)a * TPAST_ + TPAST_ - 1) * 2 + c];
    const float* pr = predrel + (size_t)ah * TFUT_ * 2 + c;
    float* pd = pred + (size_t)ah * TFUT_ * 2 + c;
    for (int t = 0; t < TFUT_; ++t) { acc += pr[t * 2]; pd[t * 2] = acc; }
}

// Embedding MLP: (2) -> relu(8) -> (16), per (agent, past-timestep).
// Output layout (T, A, 16).
__global__ __launch_bounds__(256) void embed_k(const float* __restrict__ x,
                                               const float* __restrict__ w1, const float* __restrict__ b1,
                                               const float* __restrict__ w2, const float* __restrict__ b2,
                                               float* __restrict__ emb)
{
    const int idx = blockIdx.x * 256 + threadIdx.x;   // a*TPAST + t
    if (idx >= A_ * TPAST_) return;
    const int a = idx / TPAST_, t = idx % TPAST_;
    const float x0 = x[(size_t)idx * 2], x1 = x[(size_t)idx * 2 + 1];
    float hbuf[8];
    #pragma unroll
    for (int j = 0; j < 8; ++j) hbuf[j] = fmaxf(0.f, w1[j * 2] * x0 + w1[j * 2 + 1] * x1 + b1[j]);
    float* e = emb + ((size_t)t * A_ + a) * EMB_;
    #pragma unroll
    for (int i = 0; i < 16; ++i) {
        float acc = b2[i];
        #pragma unroll
        for (int j = 0; j < 8; ++j) acc += w2[i * 8 + j] * hbuf[j];
        e[i] = acc;
    }
}

// State init (broadcast biases)
__global__ __launch_bounds__(256) void init_k(float* __restrict__ h, const float* __restrict__ h_bias,
                                              float* __restrict__ hr, const float* __restrict__ hr_bias,
                                              float* __restrict__ hf, const float* __restrict__ hf_bias,
                                              float* __restrict__ r, const float* __restrict__ init_r,
                                              float* __restrict__ mem, const float* __restrict__ mem_bias)
{
    const int idx = blockIdx.x * 256 + threadIdx.x;
    if (idx < B_ * N_ * M_) mem[idx] = mem_bias[idx & (N_ * M_ - 1)];
    if (idx < A_ * C_) { h[idx] = h_bias[idx & (C_ - 1)]; hr[idx] = hr_bias[idx & (C_ - 1)]; }
    if (idx < H_ * A_ * D_) hf[idx] = hf_bias[idx % D_];
    if (idx < A_ * M_) r[idx] = init_r[idx & (M_ - 1)];
}

extern "C" void kernel_launch(void* const* d_in, const int* in_sizes, int n_in,
                              void* d_out, int out_size, void* d_ws, size_t ws_size,
                              hipStream_t stream)
{
    const float* past       = (const float*)d_in[0];
    const float* past_rel   = (const float*)d_in[1];
    const float* ep_w1      = (const float*)d_in[2];
    const float* ep_b1      = (const float*)d_in[3];
    const float* ep_w2      = (const float*)d_in[4];
    const float* ep_b2      = (const float*)d_in[5];
    const float* er_w1      = (const float*)d_in[6];
    const float* er_b1      = (const float*)d_in[7];
    const float* er_w2      = (const float*)d_in[8];
    const float* er_b2      = (const float*)d_in[9];
    const float* enc_wih    = (const float*)d_in[10];
    const float* enc_whh    = (const float*)d_in[11];
    const float* enc_bih    = (const float*)d_in[12];
    const float* enc_bhh    = (const float*)d_in[13];
    const float* rel_wih    = (const float*)d_in[14];
    const float* rel_whh    = (const float*)d_in[15];
    const float* rel_bih    = (const float*)d_in[16];
    const float* rel_bhh    = (const float*)d_in[17];
    const float* dec_wih    = (const float*)d_in[18];
    const float* dec_whh    = (const float*)d_in[19];
    const float* dec_bih    = (const float*)d_in[20];
    const float* dec_bhh    = (const float*)d_in[21];
    const float* out_w      = (const float*)d_in[22];
    const float* out_b      = (const float*)d_in[23];
    const float* read_w     = (const float*)d_in[24];  // (5,129,256) -> (645,256)
    const float* read_b     = (const float*)d_in[25];  // (645)
    const float* write_w    = (const float*)d_in[26];  // (385,256)
    const float* write_b    = (const float*)d_in[27];
    const float* init_r     = (const float*)d_in[28];
    const float* h_bias     = (const float*)d_in[29];
    const float* h_rel_bias = (const float*)d_in[30];
    const float* h_fut_bias = (const float*)d_in[31];
    const float* mem_bias   = (const float*)d_in[32];

    float* pred    = (float*)d_out;
    float* predrel = pred + (size_t)A_ * H_ * TFUT_ * 2;   // 307200

    float* ws = (float*)d_ws;
    size_t off = 0;
    auto alloc = [&](size_t n) { float* p = ws + off; off += n; return p; };
    float* emb_p = alloc((size_t)TPAST_ * A_ * EMB_);
    float* emb_r = alloc((size_t)TPAST_ * A_ * EMB_);
    float* h0    = alloc((size_t)A_ * C_);
    float* h1    = alloc((size_t)A_ * C_);
    float* hr0   = alloc((size_t)A_ * C_);
    float* hr1   = alloc((size_t)A_ * C_);
    float* hf0   = alloc((size_t)H_ * A_ * D_);
    float* hf1   = alloc((size_t)H_ * A_ * D_);
    float* rbuf  = alloc((size_t)A_ * M_);
    float* mem   = alloc((size_t)B_ * N_ * M_);
    float* wp    = alloc((size_t)A_ * 385);
    float* rp    = alloc((size_t)A_ * 645);
    float* reads = alloc((size_t)H_ * A_ * M_);
    (void)ws_size; (void)in_sizes; (void)n_in; (void)out_size;

    init_k<<<(B_ * N_ * M_ + 255) / 256, 256, 0, stream>>>(
        h0, h_bias, hr0, h_rel_bias, hf0, h_fut_bias, rbuf, init_r, mem, mem_bias);
    embed_k<<<(A_ * TPAST_ + 255) / 256, 256, 0, stream>>>(past, ep_w1, ep_b1, ep_w2, ep_b2, emb_p);
    embed_k<<<(A_ * TPAST_ + 255) / 256, 256, 0, stream>>>(past_rel, er_w1, er_b1, er_w2, er_b2, emb_r);

    float *hc = h0, *hn = h1, *hrc = hr0, *hrn = hr1, *hfc = hf0, *hfn = hf1;
    const dim3 g_enc(A_ / 64, C_ / 64);
    const dim3 g_dec((H_ * A_) / 64, D_ / 64);
    const dim3 g_wp(A_ / 64, (385 + 63) / 64);
    const dim3 g_rp(A_ / 64, (645 + 63) / 64);

    for (int t = 0; t < TTOT_; ++t) {
        const float* ep = (t < TPAST_) ? emb_p + (size_t)t * A_ * EMB_ : nullptr;
        const float* er = (t < TPAST_) ? emb_r + (size_t)t * A_ * EMB_ : nullptr;

        // encoder GRU: x = [emb(16), r(128)]
        gru_fused<<<g_enc, 256, 0, stream>>>(ep, 16, A_, rbuf, 128,
                                             enc_wih, enc_bih, enc_whh, enc_bhh,
                                             hc, hn, A_, C_);
        // rel GRU: x = emb_r(16) (zeros in future)
        gru_fused<<<g_enc, 256, 0, stream>>>(er, 16, A_, nullptr, 0,
                                             rel_wih, rel_bih, rel_whh, rel_bhh,
                                             hrc, hrn, A_, C_);
        // write head params
        gemm_xt<<<g_wp, 256, 0, stream>>>(hn, write_w, write_b, wp, A_, 385, C_);
        // memory write
        write_mem_k<<<A_, 256, 0, stream>>>(wp, mem);
        // read head params (all 5 heads)
        gemm_xt<<<g_rp, 256, 0, stream>>>(hrn, read_w, read_b, rp, A_, 645, C_);
        // memory read -> reads, r
        read_k<<<A_, 256, 0, stream>>>(rp, mem, reads, rbuf);
        // decoder GRU: x = [h broadcast (256), reads (128)]
        gru_fused<<<g_dec, 256, 0, stream>>>(hn, C_, A_, reads, M_,
                                             dec_wih, dec_bih, dec_whh, dec_bhh,
                                             hfc, hfn, H_ * A_, D_);
        if (t >= TPAST_)
            out_k<<<(H_ * A_) / 4, 256, 0, stream>>>(hfn, out_w, out_b, predrel, t - TPAST_);

        float* tmp;
        tmp = hc; hc = hn; hn = tmp;
        tmp = hrc; hrc = hrn; hrn = tmp;
        tmp = hfc; hfc = hfn; hfn = tmp;
    }
    cumsum_k<<<(A_ * H_ * 2 + 255) / 256, 256, 0, stream>>>(past, predrel, pred);
}

// Round 2
// 11643.764 us; speedup vs baseline: 2.1145x; 2.1145x over previous
//
#include <hip/hip_runtime.h>
#include <math.h>

#define B_    64
#define APER_ 16
#define A_    1024
#define TPAST_ 20
#define TFUT_  30
#define C_    256
#define M_    128
#define N_    256
#define H_    5
#define EMB_  16
#define D_    384
#define TTOT_ 50

typedef short bf16x8 __attribute__((ext_vector_type(8)));
typedef float f32x4 __attribute__((ext_vector_type(4)));

__device__ __forceinline__ float sigmoidf_(float x) { return 1.0f / (1.0f + expf(-x)); }
__device__ __forceinline__ float softplusf_(float x) { return (x > 20.0f) ? x : log1pf(expf(x)); }
__device__ __forceinline__ unsigned short f2bf(float f) {
    unsigned u = __float_as_uint(f);
    return (unsigned short)((u + 0x7FFFu + ((u >> 16) & 1u)) >> 16);
}

// ---------------------------------------------------------------------------
// Weight fp32 -> bf16 with zero padding (rows along N, cols along K).
// ---------------------------------------------------------------------------
__global__ __launch_bounds__(256) void convert_w(const float* __restrict__ src, short* __restrict__ dst,
                                                 int srcRows, int srcK, int dstK, int total)
{
    const int idx = blockIdx.x * 256 + threadIdx.x;
    if (idx >= total) return;
    const int r = idx / dstK, k = idx % dstK;
    float v = (k < srcK && r < srcRows) ? src[(size_t)r * srcK + k] : 0.f;
    dst[idx] = (short)f2bf(v);
}

// ---------------------------------------------------------------------------
// MFMA GRU:  Hnew = GRU([X1,X2,pad], Hprev)
// X1 (bf16, K1 cols) indexed by (row & 1023); X2 (bf16, K2 cols) indexed by row.
// Wih: (3G, Kpad) bf16 zero-padded. Whh: (3G, G) bf16.
// One wave (64 thr) computes a 32x32 output tile; 6 gate accumulators.
// Fragment layout (16x16x32 bf16): A row=lane&15, k=(lane>>4)*8+r;
//                                  B col=lane&15, k=(lane>>4)*8+r;
//                                  D col=lane&15, row=(lane>>4)*4+reg.
// ---------------------------------------------------------------------------
__global__ __launch_bounds__(64) void gru_mfma(
    const short* __restrict__ X1, int K1,
    const short* __restrict__ X2, int K2,
    const short* __restrict__ Wih, int Kpad,
    const float* __restrict__ bih,
    const short* __restrict__ Hb, const short* __restrict__ Whh,
    const float* __restrict__ bhh,
    const float* __restrict__ Hprev,
    float* __restrict__ Hnew, short* __restrict__ Hnewb,
    int G)
{
    const int lane = threadIdx.x;
    const int rowBase = blockIdx.x * 32;
    const int colBase = blockIdx.y * 32;
    const int l16 = lane & 15;
    const int kb8 = (lane >> 4) * 8;

    f32x4 gi[3][2][2], gh[3][2][2];
    const f32x4 z4 = {0.f, 0.f, 0.f, 0.f};
    #pragma unroll
    for (int g = 0; g < 3; ++g)
        #pragma unroll
        for (int i = 0; i < 2; ++i)
            #pragma unroll
            for (int j = 0; j < 2; ++j) { gi[g][i][j] = z4; gh[g][i][j] = z4; }

    // gi = [X1,X2,0] @ Wih^T
    for (int kc = 0; kc < Kpad; kc += 32) {
        bf16x8 afr[2];
        const int k8 = kc + kb8;
        #pragma unroll
        for (int i = 0; i < 2; ++i) {
            const int r = rowBase + i * 16 + l16;
            bf16x8 v = {0, 0, 0, 0, 0, 0, 0, 0};
            if (k8 < K1) {
                if (X1) v = *(const bf16x8*)(X1 + (size_t)(r & 1023) * K1 + k8);
            } else if (k8 < K1 + K2) {
                v = *(const bf16x8*)(X2 + (size_t)r * K2 + (k8 - K1));
            }
            afr[i] = v;
        }
        #pragma unroll
        for (int g = 0; g < 3; ++g)
            #pragma unroll
            for (int j = 0; j < 2; ++j) {
                const bf16x8 b = *(const bf16x8*)(Wih + (size_t)(g * G + colBase + j * 16 + l16) * Kpad + k8);
                gi[g][0][j] = __builtin_amdgcn_mfma_f32_16x16x32_bf16(afr[0], b, gi[g][0][j], 0, 0, 0);
                gi[g][1][j] = __builtin_amdgcn_mfma_f32_16x16x32_bf16(afr[1], b, gi[g][1][j], 0, 0, 0);
            }
    }
    // gh = Hprev @ Whh^T
    for (int kc = 0; kc < G; kc += 32) {
        const int k8 = kc + kb8;
        bf16x8 afr[2];
        #pragma unroll
        for (int i = 0; i < 2; ++i)
            afr[i] = *(const bf16x8*)(Hb + (size_t)(rowBase + i * 16 + l16) * G + k8);
        #pragma unroll
        for (int g = 0; g < 3; ++g)
            #pragma unroll
            for (int j = 0; j < 2; ++j) {
                const bf16x8 b = *(const bf16x8*)(Whh + (size_t)(g * G + colBase + j * 16 + l16) * G + k8);
                gh[g][0][j] = __builtin_amdgcn_mfma_f32_16x16x32_bf16(afr[0], b, gh[g][0][j], 0, 0, 0);
                gh[g][1][j] = __builtin_amdgcn_mfma_f32_16x16x32_bf16(afr[1], b, gh[g][1][j], 0, 0, 0);
            }
    }

    const int r4 = (lane >> 4) * 4;
    #pragma unroll
    for (int j = 0; j < 2; ++j) {
        const int col = colBase + j * 16 + l16;
        const float bi0 = bih[col],         bh0 = bhh[col];
        const float bi1 = bih[G + col],     bh1 = bhh[G + col];
        const float bi2 = bih[2 * G + col], bh2 = bhh[2 * G + col];
        #pragma unroll
        for (int i = 0; i < 2; ++i) {
            #pragma unroll
            for (int q = 0; q < 4; ++q) {
                const int row = rowBase + i * 16 + r4 + q;
                const float rr = sigmoidf_(gi[0][i][j][q] + bi0 + gh[0][i][j][q] + bh0);
                const float zz = sigmoidf_(gi[1][i][j][q] + bi1 + gh[1][i][j][q] + bh1);
                const float nn = tanhf(gi[2][i][j][q] + bi2 + rr * (gh[2][i][j][q] + bh2));
                const float hp = Hprev[(size_t)row * G + col];
                const float hv = (1.f - zz) * nn + zz * hp;
                Hnew[(size_t)row * G + col] = hv;
                Hnewb[(size_t)row * G + col] = (short)f2bf(hv);
            }
        }
    }
}

// ---------------------------------------------------------------------------
// MFMA head GEMM: Out(R,Ncols) fp32 = Xb(R,K) @ Wb(Npad,K)^T + bias
// Wave = 32x32 tile. Wb padded with zero rows; store guarded by col<Ncols.
// ---------------------------------------------------------------------------
__global__ __launch_bounds__(64) void gemm_mfma(
    const short* __restrict__ Xb, const short* __restrict__ Wb,
    const float* __restrict__ bias, float* __restrict__ Out,
    int Ncols, int K)
{
    const int lane = threadIdx.x;
    const int rowBase = blockIdx.x * 32;
    const int colBase = blockIdx.y * 32;
    const int l16 = lane & 15;
    const int kb8 = (lane >> 4) * 8;

    const f32x4 z4 = {0.f, 0.f, 0.f, 0.f};
    f32x4 acc[2][2] = {{z4, z4}, {z4, z4}};

    for (int kc = 0; kc < K; kc += 32) {
        const int k8 = kc + kb8;
        const bf16x8 a0 = *(const bf16x8*)(Xb + (size_t)(rowBase + l16) * K + k8);
        const bf16x8 a1 = *(const bf16x8*)(Xb + (size_t)(rowBase + 16 + l16) * K + k8);
        const bf16x8 b0 = *(const bf16x8*)(Wb + (size_t)(colBase + l16) * K + k8);
        const bf16x8 b1 = *(const bf16x8*)(Wb + (size_t)(colBase + 16 + l16) * K + k8);
        acc[0][0] = __builtin_amdgcn_mfma_f32_16x16x32_bf16(a0, b0, acc[0][0], 0, 0, 0);
        acc[0][1] = __builtin_amdgcn_mfma_f32_16x16x32_bf16(a0, b1, acc[0][1], 0, 0, 0);
        acc[1][0] = __builtin_amdgcn_mfma_f32_16x16x32_bf16(a1, b0, acc[1][0], 0, 0, 0);
        acc[1][1] = __builtin_amdgcn_mfma_f32_16x16x32_bf16(a1, b1, acc[1][1], 0, 0, 0);
    }
    const int r4 = (lane >> 4) * 4;
    #pragma unroll
    for (int j = 0; j < 2; ++j) {
        const int col = colBase + j * 16 + l16;
        if (col >= Ncols) continue;
        const float bv = bias[col];
        #pragma unroll
        for (int i = 0; i < 2; ++i)
            #pragma unroll
            for (int q = 0; q < 4; ++q) {
                const int row = rowBase + i * 16 + r4 + q;
                Out[(size_t)row * Ncols + col] = acc[i][j][q] + bv;
            }
    }
}

// ---------------------------------------------------------------------------
// NTM write: per-agent banded content addressing + erase/add (fp32).
// ---------------------------------------------------------------------------
__global__ __launch_bounds__(256) void write_mem_k(const float* __restrict__ wp,
                                                   float* __restrict__ mem)
{
    const int a = blockIdx.x;
    const int b = a >> 4, p = a & 15;
    __shared__ float kw[128], er[128], ad[128], red[256], ww[16], logit[16];
    __shared__ float beta_s, knorm_s;
    const int tid = threadIdx.x;
    const float* w = wp + (size_t)a * 385;
    if (tid < 128) {
        kw[tid] = tanhf(w[tid]);
        er[tid] = sigmoidf_(w[129 + tid]);
        ad[tid] = tanhf(w[257 + tid]);
    }
    if (tid == 0) beta_s = softplusf_(w[128]);
    __syncthreads();

    red[tid] = (tid < 128) ? kw[tid] * kw[tid] : 0.f;
    __syncthreads();
    for (int s = 128; s > 0; s >>= 1) { if (tid < s) red[tid] += red[tid + s]; __syncthreads(); }
    if (tid == 0) knorm_s = sqrtf(red[0]) + 1e-16f;
    __syncthreads();

    const int s = tid >> 4, j = tid & 15;
    float dot = 0.f, ss = 0.f;
    {
        const float* mrow = mem + ((size_t)(b * N_) + p * 16 + s) * M_;
        for (int k = j; k < 128; k += 16) { float v = mrow[k]; dot += kw[k] * v; ss += v * v; }
    }
    red[tid] = dot; __syncthreads();
    for (int st = 8; st > 0; st >>= 1) { if (j < st) red[tid] += red[tid + st]; __syncthreads(); }
    float dotf = red[s * 16];
    __syncthreads();
    red[tid] = ss; __syncthreads();
    for (int st = 8; st > 0; st >>= 1) { if (j < st) red[tid] += red[tid + st]; __syncthreads(); }
    float ssf = red[s * 16];
    if (j == 0) {
        float mn = sqrtf(ssf) + 1e-16f;
        logit[s] = beta_s * (dotf / (mn * knorm_s));
    }
    __syncthreads();
    if (tid == 0) {
        float mx = -1e30f;
        for (int i = 0; i < 16; ++i) mx = fmaxf(mx, logit[i]);
        float sum = 0.f;
        for (int i = 0; i < 16; ++i) { float e = __expf(logit[i] - mx); ww[i] = e; sum += e; }
        float inv = 1.f / sum;
        for (int i = 0; i < 16; ++i) ww[i] *= inv;
    }
    __syncthreads();
    for (int idx = tid; idx < 16 * 128; idx += 256) {
        int si = idx >> 7, m = idx & 127;
        float* mp = mem + ((size_t)(b * N_) + p * 16 + si) * M_ + m;
        float wwv = ww[si];
        *mp = (*mp) * (1.f - wwv * er[m]) + wwv * ad[m];
    }
}

// ---------------------------------------------------------------------------
// NTM read (fp32 math, bf16 output): per-agent block, H heads.
// ---------------------------------------------------------------------------
__global__ __launch_bounds__(256) void read_k(const float* __restrict__ rp,
                                              const float* __restrict__ mem,
                                              short* __restrict__ reads_b)
{
    const int a = blockIdx.x;
    const int b = a >> 4, p = a & 15;
    __shared__ float kr[128], wr[256], red[256];
    __shared__ float beta_s, knorm_s;
    const int tid = threadIdx.x;

    for (int h = 0; h < H_; ++h) {
        const float* rrow = rp + (size_t)a * 645 + h * 129;
        if (tid < 128) kr[tid] = tanhf(rrow[tid]);
        if (tid == 0) beta_s = softplusf_(rrow[128]);
        __syncthreads();
        red[tid] = (tid < 128) ? kr[tid] * kr[tid] : 0.f;
        __syncthreads();
        for (int s = 128; s > 0; s >>= 1) { if (tid < s) red[tid] += red[tid + s]; __syncthreads(); }
        if (tid == 0) knorm_s = sqrtf(red[0]) + 1e-16f;
        __syncthreads();

        const float* mrow = mem + ((size_t)(b * N_) + tid) * M_;
        float dot = 0.f, ss = 0.f;
        for (int k = 0; k < 128; k += 4) {
            float4 v = *(const float4*)(mrow + k);
            dot += kr[k] * v.x + kr[k + 1] * v.y + kr[k + 2] * v.z + kr[k + 3] * v.w;
            ss += v.x * v.x + v.y * v.y + v.z * v.z + v.w * v.w;
        }
        float lg;
        if ((tid >> 4) == p) lg = -1e30f;
        else {
            float mn = sqrtf(ss) + 1e-16f;
            lg = beta_s * (dot / (mn * knorm_s));
        }
        red[tid] = lg; __syncthreads();
        for (int s = 128; s > 0; s >>= 1) { if (tid < s) red[tid] = fmaxf(red[tid], red[tid + s]); __syncthreads(); }
        float mx = red[0];
        __syncthreads();
        float e = __expf(lg - mx);
        wr[tid] = e; red[tid] = e; __syncthreads();
        for (int s = 128; s > 0; s >>= 1) { if (tid < s) red[tid] += red[tid + s]; __syncthreads(); }
        float inv = 1.f / red[0];

        if (tid < 128) {
            float acc = 0.f;
            const float* mb = mem + (size_t)(b * N_) * M_ + tid;
            for (int n = 0; n < N_; ++n) acc += wr[n] * mb[(size_t)n * M_];
            acc *= inv;
            reads_b[((size_t)h * A_ + a) * M_ + tid] = (short)f2bf(acc);
        }
        __syncthreads();
    }
}

// ---------------------------------------------------------------------------
// Output projection, cumsum, embedding, init
// ---------------------------------------------------------------------------
__global__ __launch_bounds__(256) void out_k(const float* __restrict__ hf,
                                             const float* __restrict__ out_w,
                                             const float* __restrict__ out_b,
                                             float* __restrict__ predrel, int t)
{
    const int row = blockIdx.x * 4 + (threadIdx.x >> 6);
    const int lane = threadIdx.x & 63;
    const float* hrow = hf + (size_t)row * D_;
    float a0 = 0.f, a1 = 0.f;
    for (int k = lane; k < D_; k += 64) {
        float v = hrow[k];
        a0 += v * out_w[k];
        a1 += v * out_w[D_ + k];
    }
    for (int off = 32; off > 0; off >>= 1) { a0 += __shfl_down(a0, off); a1 += __shfl_down(a1, off); }
    if (lane == 0) {
        int hh = row >> 10;
        int a = row & 1023;
        float* o = predrel + (((size_t)a * H_ + hh) * TFUT_ + t) * 2;
        o[0] = a0 + out_b[0];
        o[1] = a1 + out_b[1];
    }
}

__global__ __launch_bounds__(256) void cumsum_k(const float* __restrict__ past,
                                                const float* __restrict__ predrel,
                                                float* __restrict__ pred)
{
    const int idx = blockIdx.x * 256 + threadIdx.x;
    if (idx >= A_ * H_ * 2) return;
    const int c = idx & 1;
    const int ah = idx >> 1;
    const int a = ah / H_;
    float acc = past[((size_t)a * TPAST_ + TPAST_ - 1) * 2 + c];
    const float* pr = predrel + (size_t)ah * TFUT_ * 2 + c;
    float* pd = pred + (size_t)ah * TFUT_ * 2 + c;
    for (int t = 0; t < TFUT_; ++t) { acc += pr[t * 2]; pd[t * 2] = acc; }
}

__global__ __launch_bounds__(256) void embed_k(const float* __restrict__ x,
                                               const float* __restrict__ w1, const float* __restrict__ b1,
                                               const float* __restrict__ w2, const float* __restrict__ b2,
                                               short* __restrict__ emb)
{
    const int idx = blockIdx.x * 256 + threadIdx.x;
    if (idx >= A_ * TPAST_) return;
    const int a = idx / TPAST_, t = idx % TPAST_;
    const float x0 = x[(size_t)idx * 2], x1 = x[(size_t)idx * 2 + 1];
    float hbuf[8];
    #pragma unroll
    for (int j = 0; j < 8; ++j) hbuf[j] = fmaxf(0.f, w1[j * 2] * x0 + w1[j * 2 + 1] * x1 + b1[j]);
    short* e = emb + ((size_t)t * A_ + a) * EMB_;
    #pragma unroll
    for (int i = 0; i < 16; ++i) {
        float acc = b2[i];
        #pragma unroll
        for (int j = 0; j < 8; ++j) acc += w2[i * 8 + j] * hbuf[j];
        e[i] = (short)f2bf(acc);
    }
}

__global__ __launch_bounds__(256) void init_k(float* __restrict__ h, const float* __restrict__ h_bias, short* __restrict__ hb,
                                              float* __restrict__ hr, const float* __restrict__ hr_bias, short* __restrict__ hrb,
                                              float* __restrict__ hf, const float* __restrict__ hf_bias, short* __restrict__ hfb,
                                              short* __restrict__ reads_b, const float* __restrict__ init_r,
                                              float* __restrict__ mem, const float* __restrict__ mem_bias)
{
    const int idx = blockIdx.x * 256 + threadIdx.x;
    if (idx < B_ * N_ * M_) mem[idx] = mem_bias[idx & (N_ * M_ - 1)];
    if (idx < A_ * C_) {
        float v = h_bias[idx & (C_ - 1)];
        h[idx] = v; hb[idx] = (short)f2bf(v);
        v = hr_bias[idx & (C_ - 1)];
        hr[idx] = v; hrb[idx] = (short)f2bf(v);
    }
    if (idx < H_ * A_ * D_) {
        float v = hf_bias[idx % D_];
        hf[idx] = v; hfb[idx] = (short)f2bf(v);
    }
    if (idx < A_ * M_) reads_b[idx] = (short)f2bf(init_r[idx & (M_ - 1)]);
}

extern "C" void kernel_launch(void* const* d_in, const int* in_sizes, int n_in,
                              void* d_out, int out_size, void* d_ws, size_t ws_size,
                              hipStream_t stream)
{
    const float* past       = (const float*)d_in[0];
    const float* past_rel   = (const float*)d_in[1];
    const float* ep_w1      = (const float*)d_in[2];
    const float* ep_b1      = (const float*)d_in[3];
    const float* ep_w2      = (const float*)d_in[4];
    const float* ep_b2      = (const float*)d_in[5];
    const float* er_w1      = (const float*)d_in[6];
    const float* er_b1      = (const float*)d_in[7];
    const float* er_w2      = (const float*)d_in[8];
    const float* er_b2      = (const float*)d_in[9];
    const float* enc_wih    = (const float*)d_in[10];
    const float* enc_whh    = (const float*)d_in[11];
    const float* enc_bih    = (const float*)d_in[12];
    const float* enc_bhh    = (const float*)d_in[13];
    const float* rel_wih    = (const float*)d_in[14];
    const float* rel_whh    = (const float*)d_in[15];
    const float* rel_bih    = (const float*)d_in[16];
    const float* rel_bhh    = (const float*)d_in[17];
    const float* dec_wih    = (const float*)d_in[18];
    const float* dec_whh    = (const float*)d_in[19];
    const float* dec_bih    = (const float*)d_in[20];
    const float* dec_bhh    = (const float*)d_in[21];
    const float* out_w      = (const float*)d_in[22];
    const float* out_b      = (const float*)d_in[23];
    const float* read_w     = (const float*)d_in[24];
    const float* read_b     = (const float*)d_in[25];
    const float* write_w    = (const float*)d_in[26];
    const float* write_b    = (const float*)d_in[27];
    const float* init_r     = (const float*)d_in[28];
    const float* h_bias     = (const float*)d_in[29];
    const float* h_rel_bias = (const float*)d_in[30];
    const float* h_fut_bias = (const float*)d_in[31];
    const float* mem_bias   = (const float*)d_in[32];

    float* pred    = (float*)d_out;
    float* predrel = pred + (size_t)A_ * H_ * TFUT_ * 2;

    float* ws = (float*)d_ws;
    size_t off = 0;
    auto alloc = [&](size_t n) { float* p = ws + off; off += n; return p; };
    float* h0   = alloc((size_t)A_ * C_);
    float* h1   = alloc((size_t)A_ * C_);
    float* hr0  = alloc((size_t)A_ * C_);
    float* hr1  = alloc((size_t)A_ * C_);
    float* hf0  = alloc((size_t)H_ * A_ * D_);
    float* hf1  = alloc((size_t)H_ * A_ * D_);
    float* mem  = alloc((size_t)B_ * N_ * M_);
    float* wp   = alloc((size_t)A_ * 385);
    float* rp   = alloc((size_t)A_ * 645);

    short* sws = (short*)(ws + off);
    size_t soff = 0;
    auto salloc = [&](size_t n) { short* p = sws + soff; soff += n; return p; };
    short* emb_p_b   = salloc((size_t)TPAST_ * A_ * EMB_);
    short* emb_r_b   = salloc((size_t)TPAST_ * A_ * EMB_);
    short* hb0       = salloc((size_t)A_ * C_);
    short* hb1       = salloc((size_t)A_ * C_);
    short* hrb0      = salloc((size_t)A_ * C_);
    short* hrb1      = salloc((size_t)A_ * C_);
    short* hfb0      = salloc((size_t)H_ * A_ * D_);
    short* hfb1      = salloc((size_t)H_ * A_ * D_);
    short* reads_b   = salloc((size_t)H_ * A_ * M_);
    short* enc_wih_b = salloc((size_t)768 * 160);
    short* enc_whh_b = salloc((size_t)768 * 256);
    short* rel_wih_b = salloc((size_t)768 * 32);
    short* rel_whh_b = salloc((size_t)768 * 256);
    short* dec_wih_b = salloc((size_t)1152 * 384);
    short* dec_whh_b = salloc((size_t)1152 * 384);
    short* write_w_b = salloc((size_t)416 * 256);
    short* read_w_b  = salloc((size_t)672 * 256);
    (void)ws_size; (void)in_sizes; (void)n_in; (void)out_size;

    // Prologue: weight conversion (fp32 -> padded bf16)
    auto cvt = [&](const float* s, short* d, int sr, int sk, int dr, int dk) {
        int total = dr * dk;
        convert_w<<<(total + 255) / 256, 256, 0, stream>>>(s, d, sr, sk, dk, total);
    };
    cvt(enc_wih, enc_wih_b, 768, 144, 768, 160);
    cvt(enc_whh, enc_whh_b, 768, 256, 768, 256);
    cvt(rel_wih, rel_wih_b, 768, 16, 768, 32);
    cvt(rel_whh, rel_whh_b, 768, 256, 768, 256);
    cvt(dec_wih, dec_wih_b, 1152, 384, 1152, 384);
    cvt(dec_whh, dec_whh_b, 1152, 384, 1152, 384);
    cvt(write_w, write_w_b, 385, 256, 416, 256);
    cvt(read_w, read_w_b, 645, 256, 672, 256);

    init_k<<<(B_ * N_ * M_ + 255) / 256, 256, 0, stream>>>(
        h0, h_bias, hb0, hr0, h_rel_bias, hrb0, hf0, h_fut_bias, hfb0,
        reads_b, init_r, mem, mem_bias);
    embed_k<<<(A_ * TPAST_ + 255) / 256, 256, 0, stream>>>(past, ep_w1, ep_b1, ep_w2, ep_b2, emb_p_b);
    embed_k<<<(A_ * TPAST_ + 255) / 256, 256, 0, stream>>>(past_rel, er_w1, er_b1, er_w2, er_b2, emb_r_b);

    float *hc = h0, *hn = h1, *hrc = hr0, *hrn = hr1, *hfc = hf0, *hfn = hf1;
    short *hbc = hb0, *hbn = hb1, *hrbc = hrb0, *hrbn = hrb1, *hfbc = hfb0, *hfbn = hfb1;

    const dim3 g_enc(A_ / 32, C_ / 32);        // (32, 8)
    const dim3 g_dec((H_ * A_) / 32, D_ / 32); // (160, 12)
    const dim3 g_wp(A_ / 32, 13);              // 13*32=416 >= 385
    const dim3 g_rp(A_ / 32, 21);              // 21*32=672 >= 645

    for (int t = 0; t < TTOT_; ++t) {
        const short* ep = (t < TPAST_) ? emb_p_b + (size_t)t * A_ * EMB_ : nullptr;
        const short* er = (t < TPAST_) ? emb_r_b + (size_t)t * A_ * EMB_ : nullptr;

        // encoder GRU: x = [emb(16), r(128), pad(16)]
        gru_mfma<<<g_enc, 64, 0, stream>>>(ep, 16, reads_b, 128,
                                           enc_wih_b, 160, enc_bih,
                                           hbc, enc_whh_b, enc_bhh,
                                           hc, hn, hbn, C_);
        // rel GRU: x = [emb_r(16), pad(16)]
        gru_mfma<<<g_enc, 64, 0, stream>>>(er, 16, nullptr, 0,
                                           rel_wih_b, 32, rel_bih,
                                           hrbc, rel_whh_b, rel_bhh,
                                           hrc, hrn, hrbn, C_);
        // write head params
        gemm_mfma<<<g_wp, 64, 0, stream>>>(hbn, write_w_b, write_b, wp, 385, C_);
        // memory write
        write_mem_k<<<A_, 256, 0, stream>>>(wp, mem);
        // read head params
        gemm_mfma<<<g_rp, 64, 0, stream>>>(hrbn, read_w_b, read_b, rp, 645, C_);
        // memory read -> reads_b (bf16)
        read_k<<<A_, 256, 0, stream>>>(rp, mem, reads_b);
        // decoder GRU: x = [h(256), reads(128)]
        gru_mfma<<<g_dec, 64, 0, stream>>>(hbn, 256, reads_b, 128,
                                           dec_wih_b, 384, dec_bih,
                                           hfbc, dec_whh_b, dec_bhh,
                                           hfc, hfn, hfbn, D_);
        if (t >= TPAST_)
            out_k<<<(H_ * A_) / 4, 256, 0, stream>>>(hfn, out_w, out_b, predrel, t - TPAST_);

        float* tf;
        short* ts;
        tf = hc; hc = hn; hn = tf;      ts = hbc; hbc = hbn; hbn = ts;
        tf = hrc; hrc = hrn; hrn = tf;  ts = hrbc; hrbc = hrbn; hrbn = ts;
        tf = hfc; hfc = hfn; hfn = tf;  ts = hfbc; hfbc = hfbn; hfbn = ts;
    }
    cumsum_k<<<(A_ * H_ * 2 + 255) / 256, 256, 0, stream>>>(past, predrel, pred);
}

// Round 5
// 7182.382 us; speedup vs baseline: 3.4280x; 1.6212x over previous
//
#include <hip/hip_runtime.h>
#include <math.h>

#define B_    64
#define APER_ 16
#define A_    1024
#define TPAST_ 20
#define TFUT_  30
#define C_    256
#define M_    128
#define N_    256
#define H_    5
#define EMB_  16
#define D_    384
#define TTOT_ 50

typedef short bf16x8 __attribute__((ext_vector_type(8)));
typedef float f32x4 __attribute__((ext_vector_type(4)));

__device__ __forceinline__ float sigmoidf_(float x) { return 1.0f / (1.0f + expf(-x)); }
__device__ __forceinline__ float softplusf_(float x) { return (x > 20.0f) ? x : log1pf(expf(x)); }
__device__ __forceinline__ unsigned short f2bf(float f) {
    unsigned u = __float_as_uint(f);
    return (unsigned short)((u + 0x7FFFu + ((u >> 16) & 1u)) >> 16);
}
__device__ __forceinline__ float bf2f(short s) {
    return __uint_as_float(((unsigned)(unsigned short)s) << 16);
}

// ---------------------------------------------------------------------------
// Weight fp32 -> bf16 with zero padding (rows along N, cols along K).
// ---------------------------------------------------------------------------
__global__ __launch_bounds__(256) void convert_w(const float* __restrict__ src, short* __restrict__ dst,
                                                 int srcRows, int srcK, int dstK, int total)
{
    const int idx = blockIdx.x * 256 + threadIdx.x;
    if (idx >= total) return;
    const int r = idx / dstK, k = idx % dstK;
    float v = (k < srcK && r < srcRows) ? src[(size_t)r * srcK + k] : 0.f;
    dst[idx] = (short)f2bf(v);
}

// ---------------------------------------------------------------------------
// MFMA GRU:  Hnew = GRU([X1,X2,pad], Hprev)
// One wave = 32x32 output tile; 6 gate accumulators.
// Fragment layout (16x16x32 bf16): A row=lane&15, k=(lane>>4)*8+r;
//                                  B col=lane&15, k=(lane>>4)*8+r;
//                                  D col=lane&15, row=(lane>>4)*4+reg.
// ---------------------------------------------------------------------------
__global__ __launch_bounds__(64) void gru_mfma(
    const short* __restrict__ X1, int K1,
    const short* __restrict__ X2, int K2,
    const short* __restrict__ Wih, int Kpad,
    const float* __restrict__ bih,
    const short* __restrict__ Hb, const short* __restrict__ Whh,
    const float* __restrict__ bhh,
    const float* __restrict__ Hprev,
    float* __restrict__ Hnew, short* __restrict__ Hnewb,
    int G)
{
    const int lane = threadIdx.x;
    const int rowBase = blockIdx.x * 32;
    const int colBase = blockIdx.y * 32;
    const int l16 = lane & 15;
    const int kb8 = (lane >> 4) * 8;

    f32x4 gi[3][2][2], gh[3][2][2];
    const f32x4 z4 = {0.f, 0.f, 0.f, 0.f};
    #pragma unroll
    for (int g = 0; g < 3; ++g)
        #pragma unroll
        for (int i = 0; i < 2; ++i)
            #pragma unroll
            for (int j = 0; j < 2; ++j) { gi[g][i][j] = z4; gh[g][i][j] = z4; }

    // gi = [X1,X2,0] @ Wih^T
    for (int kc = 0; kc < Kpad; kc += 32) {
        bf16x8 afr[2];
        const int k8 = kc + kb8;
        #pragma unroll
        for (int i = 0; i < 2; ++i) {
            const int r = rowBase + i * 16 + l16;
            bf16x8 v = {0, 0, 0, 0, 0, 0, 0, 0};
            if (k8 < K1) {
                if (X1) v = *(const bf16x8*)(X1 + (size_t)(r & 1023) * K1 + k8);
            } else if (k8 < K1 + K2) {
                v = *(const bf16x8*)(X2 + (size_t)r * K2 + (k8 - K1));
            }
            afr[i] = v;
        }
        #pragma unroll
        for (int g = 0; g < 3; ++g)
            #pragma unroll
            for (int j = 0; j < 2; ++j) {
                const bf16x8 b = *(const bf16x8*)(Wih + (size_t)(g * G + colBase + j * 16 + l16) * Kpad + k8);
                gi[g][0][j] = __builtin_amdgcn_mfma_f32_16x16x32_bf16(afr[0], b, gi[g][0][j], 0, 0, 0);
                gi[g][1][j] = __builtin_amdgcn_mfma_f32_16x16x32_bf16(afr[1], b, gi[g][1][j], 0, 0, 0);
            }
    }
    // gh = Hprev @ Whh^T
    for (int kc = 0; kc < G; kc += 32) {
        const int k8 = kc + kb8;
        bf16x8 afr[2];
        #pragma unroll
        for (int i = 0; i < 2; ++i)
            afr[i] = *(const bf16x8*)(Hb + (size_t)(rowBase + i * 16 + l16) * G + k8);
        #pragma unroll
        for (int g = 0; g < 3; ++g)
            #pragma unroll
            for (int j = 0; j < 2; ++j) {
                const bf16x8 b = *(const bf16x8*)(Whh + (size_t)(g * G + colBase + j * 16 + l16) * G + k8);
                gh[g][0][j] = __builtin_amdgcn_mfma_f32_16x16x32_bf16(afr[0], b, gh[g][0][j], 0, 0, 0);
                gh[g][1][j] = __builtin_amdgcn_mfma_f32_16x16x32_bf16(afr[1], b, gh[g][1][j], 0, 0, 0);
            }
    }

    const int r4 = (lane >> 4) * 4;
    #pragma unroll
    for (int j = 0; j < 2; ++j) {
        const int col = colBase + j * 16 + l16;
        const float bi0 = bih[col],         bh0 = bhh[col];
        const float bi1 = bih[G + col],     bh1 = bhh[G + col];
        const float bi2 = bih[2 * G + col], bh2 = bhh[2 * G + col];
        #pragma unroll
        for (int i = 0; i < 2; ++i) {
            #pragma unroll
            for (int q = 0; q < 4; ++q) {
                const int row = rowBase + i * 16 + r4 + q;
                const float rr = sigmoidf_(gi[0][i][j][q] + bi0 + gh[0][i][j][q] + bh0);
                const float zz = sigmoidf_(gi[1][i][j][q] + bi1 + gh[1][i][j][q] + bh1);
                const float nn = tanhf(gi[2][i][j][q] + bi2 + rr * (gh[2][i][j][q] + bh2));
                const float hp = Hprev[(size_t)row * G + col];
                const float hv = (1.f - zz) * nn + zz * hp;
                Hnew[(size_t)row * G + col] = hv;
                Hnewb[(size_t)row * G + col] = (short)f2bf(hv);
            }
        }
    }
}

// ---------------------------------------------------------------------------
// MFMA head GEMM: Out(R,Ncols) fp32 = Xb(R,K) @ Wb(Npad,K)^T + bias
// ---------------------------------------------------------------------------
__global__ __launch_bounds__(64) void gemm_mfma(
    const short* __restrict__ Xb, const short* __restrict__ Wb,
    const float* __restrict__ bias, float* __restrict__ Out,
    int Ncols, int K)
{
    const int lane = threadIdx.x;
    const int rowBase = blockIdx.x * 32;
    const int colBase = blockIdx.y * 32;
    const int l16 = lane & 15;
    const int kb8 = (lane >> 4) * 8;

    const f32x4 z4 = {0.f, 0.f, 0.f, 0.f};
    f32x4 acc[2][2] = {{z4, z4}, {z4, z4}};

    for (int kc = 0; kc < K; kc += 32) {
        const int k8 = kc + kb8;
        const bf16x8 a0 = *(const bf16x8*)(Xb + (size_t)(rowBase + l16) * K + k8);
        const bf16x8 a1 = *(const bf16x8*)(Xb + (size_t)(rowBase + 16 + l16) * K + k8);
        const bf16x8 b0 = *(const bf16x8*)(Wb + (size_t)(colBase + l16) * K + k8);
        const bf16x8 b1 = *(const bf16x8*)(Wb + (size_t)(colBase + 16 + l16) * K + k8);
        acc[0][0] = __builtin_amdgcn_mfma_f32_16x16x32_bf16(a0, b0, acc[0][0], 0, 0, 0);
        acc[0][1] = __builtin_amdgcn_mfma_f32_16x16x32_bf16(a0, b1, acc[0][1], 0, 0, 0);
        acc[1][0] = __builtin_amdgcn_mfma_f32_16x16x32_bf16(a1, b0, acc[1][0], 0, 0, 0);
        acc[1][1] = __builtin_amdgcn_mfma_f32_16x16x32_bf16(a1, b1, acc[1][1], 0, 0, 0);
    }
    const int r4 = (lane >> 4) * 4;
    #pragma unroll
    for (int j = 0; j < 2; ++j) {
        const int col = colBase + j * 16 + l16;
        if (col >= Ncols) continue;
        const float bv = bias[col];
        #pragma unroll
        for (int i = 0; i < 2; ++i)
            #pragma unroll
            for (int q = 0; q < 4; ++q) {
                const int row = rowBase + i * 16 + r4 + q;
                Out[(size_t)row * Ncols + col] = acc[i][j][q] + bv;
            }
    }
}

// ---------------------------------------------------------------------------
// NTM write: per-agent banded content addressing + erase/add (fp32).
// Emits per-slot norms of the updated band (fp32) for the read kernel.
// ---------------------------------------------------------------------------
__global__ __launch_bounds__(256) void write_mem_k(const float* __restrict__ wp,
                                                   float* __restrict__ mem,
                                                   float* __restrict__ normsG)
{
    const int a = blockIdx.x;
    const int b = a >> 4, p = a & 15;
    __shared__ float kw[128], er[128], ad[128], red[256], ww[16], logit[16];
    __shared__ float buf[2048];
    __shared__ float beta_s, knorm_s;
    const int tid = threadIdx.x;
    const float* w = wp + (size_t)a * 385;
    if (tid < 128) {
        kw[tid] = tanhf(w[tid]);
        er[tid] = sigmoidf_(w[129 + tid]);
        ad[tid] = tanhf(w[257 + tid]);
    }
    if (tid == 0) beta_s = softplusf_(w[128]);
    __syncthreads();

    red[tid] = (tid < 128) ? kw[tid] * kw[tid] : 0.f;
    __syncthreads();
    for (int s = 128; s > 0; s >>= 1) { if (tid < s) red[tid] += red[tid + s]; __syncthreads(); }
    if (tid == 0) knorm_s = sqrtf(red[0]) + 1e-16f;
    __syncthreads();

    const int s = tid >> 4, j = tid & 15;
    float dot = 0.f, ss = 0.f;
    {
        const float* mrow = mem + ((size_t)(b * N_) + p * 16 + s) * M_;
        for (int k = j; k < 128; k += 16) { float v = mrow[k]; dot += kw[k] * v; ss += v * v; }
    }
    red[tid] = dot; __syncthreads();
    for (int st = 8; st > 0; st >>= 1) { if (j < st) red[tid] += red[tid + st]; __syncthreads(); }
    float dotf = red[s * 16];
    __syncthreads();
    red[tid] = ss; __syncthreads();
    for (int st = 8; st > 0; st >>= 1) { if (j < st) red[tid] += red[tid + st]; __syncthreads(); }
    float ssf = red[s * 16];
    if (j == 0) {
        float mn = sqrtf(ssf) + 1e-16f;
        logit[s] = beta_s * (dotf / (mn * knorm_s));
    }
    __syncthreads();
    if (tid == 0) {
        float mx = -1e30f;
        for (int i = 0; i < 16; ++i) mx = fmaxf(mx, logit[i]);
        float sum = 0.f;
        for (int i = 0; i < 16; ++i) { float e = __expf(logit[i] - mx); ww[i] = e; sum += e; }
        float inv = 1.f / sum;
        for (int i = 0; i < 16; ++i) ww[i] *= inv;
    }
    __syncthreads();
    for (int idx = tid; idx < 16 * 128; idx += 256) {
        int si = idx >> 7, m = idx & 127;
        size_t g = ((size_t)(b * N_) + p * 16 + si) * M_ + m;
        float wwv = ww[si];
        float v = mem[g] * (1.f - wwv * er[m]) + wwv * ad[m];
        mem[g] = v;
        buf[idx] = v;
    }
    __syncthreads();
    // per-slot norms of the updated band (fp32)
    {
        float ssq = 0.f;
        #pragma unroll
        for (int i = 0; i < 8; ++i) { float v = buf[s * 128 + j + 16 * i]; ssq += v * v; }
        #pragma unroll
        for (int m = 1; m < 16; m <<= 1) ssq += __shfl_xor(ssq, m);
        if (j == 0) normsG[b * N_ + p * 16 + s] = sqrtf(ssq) + 1e-16f;
    }
}

// ---------------------------------------------------------------------------
// NTM read v4: one block per (scene, head). 256 threads = 4 waves.
// Each wave covers 64 slots via FOUR 16-slot B-fragments (full 256 coverage —
// the round-3/4 bug was covering only 2 of 4 sub-tiles).
// Sims via error-compensated hi/lo bf16 MFMA (inputs fp32, split on the fly):
//   dot(a,b) = hi_a*hi_b + hi_a*lo_b + lo_a*hi_b   (lo*lo ~ 2^-18, dropped)
// Masked softmax with 16-lane shuffle reductions; PV in fp32 from fp32 mem.
// ---------------------------------------------------------------------------
__global__ __launch_bounds__(256) void read_k2(const float* __restrict__ rp,
                                               const float* __restrict__ mem,
                                               const float* __restrict__ normsG,
                                               short* __restrict__ reads_b)
{
    const int b = blockIdx.x;   // scene
    const int h = blockIdx.y;   // head
    __shared__ __align__(16) float kq[16 * 132];
    __shared__ float S[16 * 260];
    __shared__ float beta_s[16], knorm_s[16], inv_s[16];
    const int t = threadIdx.x;
    const int a = t >> 4;        // agent within scene
    const int sub = t & 15;

    // P0: kq = tanh(kr) (fp32 LDS), per-agent knorm & beta
    {
        const float* base = rp + ((size_t)(b * 16 + a)) * 645 + h * 129;
        const int k0 = sub * 8;
        float v[8]; float ss = 0.f;
        #pragma unroll
        for (int r = 0; r < 8; ++r) { v[r] = tanhf(base[k0 + r]); ss += v[r] * v[r]; }
        float* dst = kq + a * 132 + k0;
        *(float4*)dst = make_float4(v[0], v[1], v[2], v[3]);
        *(float4*)(dst + 4) = make_float4(v[4], v[5], v[6], v[7]);
        #pragma unroll
        for (int m = 1; m < 16; m <<= 1) ss += __shfl_xor(ss, m);
        if (sub == 0) {
            knorm_s[a] = sqrtf(ss) + 1e-16f;
            beta_s[a] = softplusf_(base[128]);
        }
    }
    __syncthreads();

    // P1: sims via hi/lo MFMA -> masked scaled logits into S[agent][slot]
    {
        const int wave = t >> 6, lane = t & 63;
        const int l16 = lane & 15, kb8 = (lane >> 4) * 8;
        const int slotBase = wave * 64;
        const f32x4 z4 = {0.f, 0.f, 0.f, 0.f};
        f32x4 acc[4] = {z4, z4, z4, z4};
        const float* mb = mem + (size_t)b * N_ * M_;
        #pragma unroll
        for (int kc = 0; kc < 128; kc += 32) {
            // A: agent l16, k = kc+kb8 .. +7  (fp32 LDS -> hi/lo bf16)
            const float* ap = kq + l16 * 132 + kc + kb8;
            bf16x8 ah, al;
            #pragma unroll
            for (int r = 0; r < 8; ++r) {
                const float av = ap[r];
                const short hv = (short)f2bf(av);
                ah[r] = hv; al[r] = (short)f2bf(av - bf2f(hv));
            }
            // B: 4 slot sub-tiles of 16 (full 64-slot coverage per wave)
            #pragma unroll
            for (int tt = 0; tt < 4; ++tt) {
                const float* bp = mb + (size_t)(slotBase + tt * 16 + l16) * M_ + kc + kb8;
                bf16x8 bh, bl;
                #pragma unroll
                for (int r = 0; r < 8; ++r) {
                    const float bv = bp[r];
                    const short hv = (short)f2bf(bv);
                    bh[r] = hv; bl[r] = (short)f2bf(bv - bf2f(hv));
                }
                acc[tt] = __builtin_amdgcn_mfma_f32_16x16x32_bf16(ah, bh, acc[tt], 0, 0, 0);
                acc[tt] = __builtin_amdgcn_mfma_f32_16x16x32_bf16(ah, bl, acc[tt], 0, 0, 0);
                acc[tt] = __builtin_amdgcn_mfma_f32_16x16x32_bf16(al, bh, acc[tt], 0, 0, 0);
            }
        }
        const int r4 = (lane >> 4) * 4;
        #pragma unroll
        for (int tt = 0; tt < 4; ++tt) {
            const int slot = slotBase + tt * 16 + l16;
            const float nv = normsG[b * N_ + slot];
            #pragma unroll
            for (int q = 0; q < 4; ++q) {
                const int aq = r4 + q;
                const float lg = ((slot >> 4) == aq) ? -1e30f
                               : beta_s[aq] * acc[tt][q] / (nv * knorm_s[aq]);
                S[aq * 260 + slot] = lg;
            }
        }
    }
    __syncthreads();

    // P2: per-agent softmax over 256 slots (16 threads per agent)
    {
        float mx = -1e30f;
        #pragma unroll
        for (int i = 0; i < 16; ++i) mx = fmaxf(mx, S[a * 260 + sub + 16 * i]);
        #pragma unroll
        for (int m = 1; m < 16; m <<= 1) mx = fmaxf(mx, __shfl_xor(mx, m));
        float e[16]; float sum = 0.f;
        #pragma unroll
        for (int i = 0; i < 16; ++i) { e[i] = __expf(S[a * 260 + sub + 16 * i] - mx); sum += e[i]; }
        #pragma unroll
        for (int i = 0; i < 16; ++i) S[a * 260 + sub + 16 * i] = e[i];
        #pragma unroll
        for (int m = 1; m < 16; m <<= 1) sum += __shfl_xor(sum, m);
        if (sub == 0) inv_s[a] = 1.f / sum;
    }
    __syncthreads();

    // P3: PV fp32 — reads[a][m] = inv * sum_n P[a][n] * mem[n][m]
    {
        const int m0 = sub * 8;
        const float* mb = mem + (size_t)b * N_ * M_ + m0;
        float acc[8];
        #pragma unroll
        for (int r = 0; r < 8; ++r) acc[r] = 0.f;
        const float* Sa = S + a * 260;
        #pragma unroll 4
        for (int n = 0; n < N_; ++n) {
            const float w = Sa[n];
            const float4 v0 = *(const float4*)(mb + (size_t)n * M_);
            const float4 v1 = *(const float4*)(mb + (size_t)n * M_ + 4);
            acc[0] = fmaf(w, v0.x, acc[0]); acc[1] = fmaf(w, v0.y, acc[1]);
            acc[2] = fmaf(w, v0.z, acc[2]); acc[3] = fmaf(w, v0.w, acc[3]);
            acc[4] = fmaf(w, v1.x, acc[4]); acc[5] = fmaf(w, v1.y, acc[5]);
            acc[6] = fmaf(w, v1.z, acc[6]); acc[7] = fmaf(w, v1.w, acc[7]);
        }
        const float inv = inv_s[a];
        short pk[8];
        #pragma unroll
        for (int r = 0; r < 8; ++r) pk[r] = (short)f2bf(acc[r] * inv);
        *(bf16x8*)(reads_b + ((size_t)h * A_ + b * 16 + a) * M_ + m0) = *(bf16x8*)pk;
    }
}

// ---------------------------------------------------------------------------
// Output projection, cumsum, embedding, init
// ---------------------------------------------------------------------------
__global__ __launch_bounds__(256) void out_k(const float* __restrict__ hf,
                                             const float* __restrict__ out_w,
                                             const float* __restrict__ out_b,
                                             float* __restrict__ predrel, int t)
{
    const int row = blockIdx.x * 4 + (threadIdx.x >> 6);
    const int lane = threadIdx.x & 63;
    const float* hrow = hf + (size_t)row * D_;
    float a0 = 0.f, a1 = 0.f;
    for (int k = lane; k < D_; k += 64) {
        float v = hrow[k];
        a0 += v * out_w[k];
        a1 += v * out_w[D_ + k];
    }
    for (int off = 32; off > 0; off >>= 1) { a0 += __shfl_down(a0, off); a1 += __shfl_down(a1, off); }
    if (lane == 0) {
        int hh = row >> 10;
        int a = row & 1023;
        float* o = predrel + (((size_t)a * H_ + hh) * TFUT_ + t) * 2;
        o[0] = a0 + out_b[0];
        o[1] = a1 + out_b[1];
    }
}

__global__ __launch_bounds__(256) void cumsum_k(const float* __restrict__ past,
                                                const float* __restrict__ predrel,
                                                float* __restrict__ pred)
{
    const int idx = blockIdx.x * 256 + threadIdx.x;
    if (idx >= A_ * H_ * 2) return;
    const int c = idx & 1;
    const int ah = idx >> 1;
    const int a = ah / H_;
    float acc = past[((size_t)a * TPAST_ + TPAST_ - 1) * 2 + c];
    const float* pr = predrel + (size_t)ah * TFUT_ * 2 + c;
    float* pd = pred + (size_t)ah * TFUT_ * 2 + c;
    for (int t = 0; t < TFUT_; ++t) { acc += pr[t * 2]; pd[t * 2] = acc; }
}

__global__ __launch_bounds__(256) void embed_k(const float* __restrict__ x,
                                               const float* __restrict__ w1, const float* __restrict__ b1,
                                               const float* __restrict__ w2, const float* __restrict__ b2,
                                               short* __restrict__ emb)
{
    const int idx = blockIdx.x * 256 + threadIdx.x;
    if (idx >= A_ * TPAST_) return;
    const int a = idx / TPAST_, t = idx % TPAST_;
    const float x0 = x[(size_t)idx * 2], x1 = x[(size_t)idx * 2 + 1];
    float hbuf[8];
    #pragma unroll
    for (int j = 0; j < 8; ++j) hbuf[j] = fmaxf(0.f, w1[j * 2] * x0 + w1[j * 2 + 1] * x1 + b1[j]);
    short* e = emb + ((size_t)t * A_ + a) * EMB_;
    #pragma unroll
    for (int i = 0; i < 16; ++i) {
        float acc = b2[i];
        #pragma unroll
        for (int j = 0; j < 8; ++j) acc += w2[i * 8 + j] * hbuf[j];
        e[i] = (short)f2bf(acc);
    }
}

__global__ __launch_bounds__(256) void init_k(float* __restrict__ h, const float* __restrict__ h_bias, short* __restrict__ hb,
                                              float* __restrict__ hr, const float* __restrict__ hr_bias, short* __restrict__ hrb,
                                              float* __restrict__ hf, const float* __restrict__ hf_bias, short* __restrict__ hfb,
                                              short* __restrict__ reads_b, const float* __restrict__ init_r,
                                              float* __restrict__ mem,
                                              float* __restrict__ normsG, const float* __restrict__ mem_bias)
{
    const int idx = blockIdx.x * 256 + threadIdx.x;
    if (idx < B_ * N_ * M_) mem[idx] = mem_bias[idx & (N_ * M_ - 1)];
    if (idx < B_ * N_) {
        const float* r = mem_bias + (size_t)(idx & (N_ - 1)) * M_;
        float ss = 0.f;
        for (int k = 0; k < M_; ++k) ss += r[k] * r[k];
        normsG[idx] = sqrtf(ss) + 1e-16f;
    }
    if (idx < A_ * C_) {
        float v = h_bias[idx & (C_ - 1)];
        h[idx] = v; hb[idx] = (short)f2bf(v);
        v = hr_bias[idx & (C_ - 1)];
        hr[idx] = v; hrb[idx] = (short)f2bf(v);
    }
    if (idx < H_ * A_ * D_) {
        float v = hf_bias[idx % D_];
        hf[idx] = v; hfb[idx] = (short)f2bf(v);
    }
    if (idx < A_ * M_) reads_b[idx] = (short)f2bf(init_r[idx & (M_ - 1)]);
}

extern "C" void kernel_launch(void* const* d_in, const int* in_sizes, int n_in,
                              void* d_out, int out_size, void* d_ws, size_t ws_size,
                              hipStream_t stream)
{
    const float* past       = (const float*)d_in[0];
    const float* past_rel   = (const float*)d_in[1];
    const float* ep_w1      = (const float*)d_in[2];
    const float* ep_b1      = (const float*)d_in[3];
    const float* ep_w2      = (const float*)d_in[4];
    const float* ep_b2      = (const float*)d_in[5];
    const float* er_w1      = (const float*)d_in[6];
    const float* er_b1      = (const float*)d_in[7];
    const float* er_w2      = (const float*)d_in[8];
    const float* er_b2      = (const float*)d_in[9];
    const float* enc_wih    = (const float*)d_in[10];
    const float* enc_whh    = (const float*)d_in[11];
    const float* enc_bih    = (const float*)d_in[12];
    const float* enc_bhh    = (const float*)d_in[13];
    const float* rel_wih    = (const float*)d_in[14];
    const float* rel_whh    = (const float*)d_in[15];
    const float* rel_bih    = (const float*)d_in[16];
    const float* rel_bhh    = (const float*)d_in[17];
    const float* dec_wih    = (const float*)d_in[18];
    const float* dec_whh    = (const float*)d_in[19];
    const float* dec_bih    = (const float*)d_in[20];
    const float* dec_bhh    = (const float*)d_in[21];
    const float* out_w      = (const float*)d_in[22];
    const float* out_b      = (const float*)d_in[23];
    const float* read_w     = (const float*)d_in[24];
    const float* read_b     = (const float*)d_in[25];
    const float* write_w    = (const float*)d_in[26];
    const float* write_b    = (const float*)d_in[27];
    const float* init_r     = (const float*)d_in[28];
    const float* h_bias     = (const float*)d_in[29];
    const float* h_rel_bias = (const float*)d_in[30];
    const float* h_fut_bias = (const float*)d_in[31];
    const float* mem_bias   = (const float*)d_in[32];

    float* pred    = (float*)d_out;
    float* predrel = pred + (size_t)A_ * H_ * TFUT_ * 2;

    float* ws = (float*)d_ws;
    size_t off = 0;
    auto alloc = [&](size_t n) { float* p = ws + off; off += n; return p; };
    float* h0     = alloc((size_t)A_ * C_);
    float* h1     = alloc((size_t)A_ * C_);
    float* hr0    = alloc((size_t)A_ * C_);
    float* hr1    = alloc((size_t)A_ * C_);
    float* hf0    = alloc((size_t)H_ * A_ * D_);
    float* hf1    = alloc((size_t)H_ * A_ * D_);
    float* mem    = alloc((size_t)B_ * N_ * M_);
    float* wp     = alloc((size_t)A_ * 385);
    float* rp     = alloc((size_t)A_ * 645);
    float* normsG = alloc((size_t)B_ * N_);

    short* sws = (short*)(ws + off);
    size_t soff = 0;
    auto salloc = [&](size_t n) { short* p = sws + soff; soff += n; return p; };
    short* emb_p_b   = salloc((size_t)TPAST_ * A_ * EMB_);
    short* emb_r_b   = salloc((size_t)TPAST_ * A_ * EMB_);
    short* hb0       = salloc((size_t)A_ * C_);
    short* hb1       = salloc((size_t)A_ * C_);
    short* hrb0      = salloc((size_t)A_ * C_);
    short* hrb1      = salloc((size_t)A_ * C_);
    short* hfb0      = salloc((size_t)H_ * A_ * D_);
    short* hfb1      = salloc((size_t)H_ * A_ * D_);
    short* reads_b   = salloc((size_t)H_ * A_ * M_);
    short* enc_wih_b = salloc((size_t)768 * 160);
    short* enc_whh_b = salloc((size_t)768 * 256);
    short* rel_wih_b = salloc((size_t)768 * 32);
    short* rel_whh_b = salloc((size_t)768 * 256);
    short* dec_wih_b = salloc((size_t)1152 * 384);
    short* dec_whh_b = salloc((size_t)1152 * 384);
    short* write_w_b = salloc((size_t)416 * 256);
    short* read_w_b  = salloc((size_t)672 * 256);
    (void)ws_size; (void)in_sizes; (void)n_in; (void)out_size;

    auto cvt = [&](const float* s, short* d, int sr, int sk, int dr, int dk) {
        int total = dr * dk;
        convert_w<<<(total + 255) / 256, 256, 0, stream>>>(s, d, sr, sk, dk, total);
    };
    cvt(enc_wih, enc_wih_b, 768, 144, 768, 160);
    cvt(enc_whh, enc_whh_b, 768, 256, 768, 256);
    cvt(rel_wih, rel_wih_b, 768, 16, 768, 32);
    cvt(rel_whh, rel_whh_b, 768, 256, 768, 256);
    cvt(dec_wih, dec_wih_b, 1152, 384, 1152, 384);
    cvt(dec_whh, dec_whh_b, 1152, 384, 1152, 384);
    cvt(write_w, write_w_b, 385, 256, 416, 256);
    cvt(read_w, read_w_b, 645, 256, 672, 256);

    init_k<<<(B_ * N_ * M_ + 255) / 256, 256, 0, stream>>>(
        h0, h_bias, hb0, hr0, h_rel_bias, hrb0, hf0, h_fut_bias, hfb0,
        reads_b, init_r, mem, normsG, mem_bias);
    embed_k<<<(A_ * TPAST_ + 255) / 256, 256, 0, stream>>>(past, ep_w1, ep_b1, ep_w2, ep_b2, emb_p_b);
    embed_k<<<(A_ * TPAST_ + 255) / 256, 256, 0, stream>>>(past_rel, er_w1, er_b1, er_w2, er_b2, emb_r_b);

    float *hc = h0, *hn = h1, *hrc = hr0, *hrn = hr1, *hfc = hf0, *hfn = hf1;
    short *hbc = hb0, *hbn = hb1, *hrbc = hrb0, *hrbn = hrb1, *hfbc = hfb0, *hfbn = hfb1;

    const dim3 g_enc(A_ / 32, C_ / 32);        // (32, 8)
    const dim3 g_dec((H_ * A_) / 32, D_ / 32); // (160, 12)
    const dim3 g_wp(A_ / 32, 13);              // 13*32=416 >= 385
    const dim3 g_rp(A_ / 32, 21);              // 21*32=672 >= 645
    const dim3 g_read(B_, H_);                 // (64, 5)

    for (int t = 0; t < TTOT_; ++t) {
        const short* ep = (t < TPAST_) ? emb_p_b + (size_t)t * A_ * EMB_ : nullptr;
        const short* er = (t < TPAST_) ? emb_r_b + (size_t)t * A_ * EMB_ : nullptr;

        // encoder GRU: x = [emb(16), r(128), pad(16)]
        gru_mfma<<<g_enc, 64, 0, stream>>>(ep, 16, reads_b, 128,
                                           enc_wih_b, 160, enc_bih,
                                           hbc, enc_whh_b, enc_bhh,
                                           hc, hn, hbn, C_);
        // rel GRU: x = [emb_r(16), pad(16)]
        gru_mfma<<<g_enc, 64, 0, stream>>>(er, 16, nullptr, 0,
                                           rel_wih_b, 32, rel_bih,
                                           hrbc, rel_whh_b, rel_bhh,
                                           hrc, hrn, hrbn, C_);
        // write head params
        gemm_mfma<<<g_wp, 64, 0, stream>>>(hbn, write_w_b, write_b, wp, 385, C_);
        // memory write (+ norms)
        write_mem_k<<<A_, 256, 0, stream>>>(wp, mem, normsG);
        // read head params
        gemm_mfma<<<g_rp, 64, 0, stream>>>(hrbn, read_w_b, read_b, rp, 645, C_);
        // memory read -> reads_b (bf16)
        read_k2<<<g_read, 256, 0, stream>>>(rp, mem, normsG, reads_b);
        // decoder GRU: x = [h(256), reads(128)]
        gru_mfma<<<g_dec, 64, 0, stream>>>(hbn, 256, reads_b, 128,
                                           dec_wih_b, 384, dec_bih,
                                           hfbc, dec_whh_b, dec_bhh,
                                           hfc, hfn, hfbn, D_);
        if (t >= TPAST_)
            out_k<<<(H_ * A_) / 4, 256, 0, stream>>>(hfn, out_w, out_b, predrel, t - TPAST_);

        float* tf;
        short* ts;
        tf = hc; hc = hn; hn = tf;      ts = hbc; hbc = hbn; hbn = ts;
        tf = hrc; hrc = hrn; hrn = tf;  ts = hrbc; hrbc = hrbn; hrbn = ts;
        tf = hfc; hfc = hfn; hfn = tf;  ts = hfbc; hfbc = hfbn; hfbn = ts;
    }
    cumsum_k<<<(A_ * H_ * 2 + 255) / 256, 256, 0, stream>>>(past, predrel, pred);
}